// Round 1
// baseline (120.634 us; speedup 1.0000x reference)
//
#include <hip/hip_runtime.h>

// CompactBilinearPooling: count-sketch (scatter-add) + circular conv via FFT.
// B=256 rows, D=4096 features, O=N=16384 output bins.
// One workgroup per row; whole complex signal lives in LDS (128 KB of 160 KB).
// Packing trick: z = y1 + i*y2, one forward FFT; Y1[f]*Y2[f] =
// (Z[f]^2 - conj(Z[N-f])^2) / (4i); one inverse FFT; take real/N.

#define FFT_N    16384
#define FFT_LOGN 14
#define BLOCK    1024
#define DIM      4096

__device__ __forceinline__ float2 cmul(float2 a, float2 b) {
    return make_float2(a.x * b.x - a.y * b.y, a.x * b.y + a.y * b.x);
}

__launch_bounds__(BLOCK, 1)
__global__ void cbp_fft_kernel(const float* __restrict__ x1,
                               const float* __restrict__ x2,
                               const int* __restrict__ h1,
                               const float* __restrict__ s1,
                               float* __restrict__ out) {
    __shared__ float2 z[FFT_N];   // 128 KB
    const int tid = threadIdx.x;
    const int b   = blockIdx.x;

    // ---- zero the sketch buffers ----
    #pragma unroll
    for (int j = tid; j < FFT_N; j += BLOCK) z[j] = make_float2(0.f, 0.f);
    __syncthreads();

    // ---- count-sketch scatter: z.x += s*x1, z.y += s*x2 at bucket h ----
    const float* x1r = x1 + (size_t)b * DIM;
    const float* x2r = x2 + (size_t)b * DIM;
    for (int d = tid; d < DIM; d += BLOCK) {
        float s = s1[d];
        int   h = h1[d];
        atomicAdd(&z[h].x, s * x1r[d]);
        atomicAdd(&z[h].y, s * x2r[d]);
    }
    __syncthreads();

    // ---- forward DIF FFT: natural order in, bit-reversed order out ----
    for (int m = FFT_N >> 1; m >= 1; m >>= 1) {
        const float ang_scale = -3.14159265358979323846f / (float)m;
        for (int t = tid; t < (FFT_N >> 1); t += BLOCK) {
            int k  = t & (m - 1);
            int i0 = ((t & ~(m - 1)) << 1) | k;
            int i1 = i0 + m;
            float2 a = z[i0];
            float2 c = z[i1];
            float2 sum = make_float2(a.x + c.x, a.y + c.y);
            float2 dif = make_float2(a.x - c.x, a.y - c.y);
            float sw, cw;
            __sincosf(ang_scale * (float)k, &sw, &cw);
            z[i0] = sum;
            z[i1] = cmul(dif, make_float2(cw, sw));
        }
        __syncthreads();
    }

    // ---- pointwise product in the bit-reversed domain ----
    // position j holds Z[f] with f = rev(j); partner freq fp = (N-f) mod N
    // sits at position jp = rev(fp). Pair {j,jp} is owned by the lower f, so
    // reads/writes are pair-local: no intra-phase sync needed.
    for (int j = tid; j < FFT_N; j += BLOCK) {
        int f  = (int)(__brev((unsigned)j) >> (32 - FFT_LOGN));
        int fp = (FFT_N - f) & (FFT_N - 1);
        if (f < fp) {
            int jp = (int)(__brev((unsigned)fp) >> (32 - FFT_LOGN));
            float2 a = z[j];    // Z[f]
            float2 c = z[jp];   // Z[N-f]
            // x = Z[f]^2 - conj(Z[N-f])^2 ;  P[f] = x/(4i) = (x.im/4, -x.re/4)
            float ar = a.x * a.x - a.y * a.y;
            float cr = c.x * c.x - c.y * c.y;
            float xr = ar - cr;
            float xi = 2.f * (a.x * a.y + c.x * c.y);
            z[j]  = make_float2(0.25f * xi, -0.25f * xr);
            // P[fp]: roles swapped (xr negates, xi identical)
            z[jp] = make_float2(0.25f * xi,  0.25f * xr);
        } else if (f == fp) {   // f == 0 or f == N/2: self-paired
            float2 a = z[j];
            z[j] = make_float2(a.x * a.y, 0.f);
        }
    }
    __syncthreads();

    // ---- inverse DIT FFT: bit-reversed in, natural order out ----
    for (int m = 1; m <= (FFT_N >> 1); m <<= 1) {
        const float ang_scale = 3.14159265358979323846f / (float)m;
        for (int t = tid; t < (FFT_N >> 1); t += BLOCK) {
            int k  = t & (m - 1);
            int i0 = ((t & ~(m - 1)) << 1) | k;
            int i1 = i0 + m;
            float sw, cw;
            __sincosf(ang_scale * (float)k, &sw, &cw);
            float2 a  = z[i0];
            float2 bw = cmul(z[i1], make_float2(cw, sw));
            z[i0] = make_float2(a.x + bw.x, a.y + bw.y);
            z[i1] = make_float2(a.x - bw.x, a.y - bw.y);
        }
        __syncthreads();
    }

    // ---- store real part, scaled by 1/N ----
    float* outr = out + (size_t)b * FFT_N;
    const float inv_n = 1.0f / (float)FFT_N;
    for (int j = tid; j < FFT_N; j += BLOCK) {
        outr[j] = z[j].x * inv_n;
    }
}

extern "C" void kernel_launch(void* const* d_in, const int* in_sizes, int n_in,
                              void* d_out, int out_size, void* d_ws, size_t ws_size,
                              hipStream_t stream) {
    const float* x1 = (const float*)d_in[0];
    const float* x2 = (const float*)d_in[1];
    const int*   h1 = (const int*)d_in[2];
    const float* s1 = (const float*)d_in[3];
    float* out = (float*)d_out;
    const int B = in_sizes[0] / DIM;   // 256
    cbp_fft_kernel<<<B, BLOCK, 0, stream>>>(x1, x2, h1, s1, out);
}

// Round 2
// 103.306 us; speedup vs baseline: 1.1677x; 1.1677x over previous
//
#include <hip/hip_runtime.h>

// CompactBilinearPooling: count-sketch + circular conv via FFT (B=256, D=4096, N=16384).
// R2: register-batched FFT. Each thread owns a 16-element digit; 14 radix-2
// stages done as 4 LDS passes (strides 1024/64/4/1) fwd + same inverse.
// Twiddles: one sincos per group + complex-squaring chain + literal sub-twiddles.
// LDS layout padded slot(e)=e+(e>>4) -> all four stride patterns are at the
// b64 bank minimum (4 words/bank/wave).

#define FFT_N   16384
#define LOGN    14
#define BLOCK   1024
#define DIM     4096
#define SLOT(e) ((e) + ((e) >> 4))
#define LDS_SLOTS 17408   // SLOT(16383)=17406 -> 17408 float2 = 139264 B

__device__ __forceinline__ float2 cmul(float2 a, float2 b) {
    return make_float2(a.x * b.x - a.y * b.y, a.x * b.y + a.y * b.x);
}
__device__ __forceinline__ float2 csqr(float2 a) {
    return make_float2(a.x * a.x - a.y * a.y, 2.f * a.x * a.y);
}

// Sub-twiddle tables: cos(pi*j/8), sin(pi*j/8), j=0..7 (indexed jp<<(3-p))
#define CT0 1.0f
#define DECL_TW_TABLES \
    const float CT[8] = {1.f, 0.92387953f, 0.70710678f, 0.38268343f, 0.f, -0.38268343f, -0.70710678f, -0.92387953f}; \
    const float ST[8] = {0.f, 0.38268343f, 0.70710678f, 0.92387953f, 1.f, 0.92387953f, 0.70710678f, 0.38268343f};

// Forward DIF stages p = PMAX..0 on 16 registers.
// W[p] = exp(i*phi*2^(3-p)); butterfly twiddle T = W[p]*exp(-i*pi*jp/2^p).
template<int PMAX>
__device__ __forceinline__ void fft16_dif(float2* r, float phi) {
    DECL_TW_TABLES
    float2 W[4];
    if (PMAX == 3) {
        __sincosf(phi, &W[3].y, &W[3].x);
        W[2] = csqr(W[3]); W[1] = csqr(W[2]); W[0] = csqr(W[1]);
    } else {
        W[0] = W[1] = W[2] = W[3] = make_float2(1.f, 0.f);
    }
    #pragma unroll
    for (int p = PMAX; p >= 0; --p) {
        #pragma unroll
        for (int h = 0; h < 8; ++h) {
            const int jp = h & ((1 << p) - 1);
            const int j  = ((h >> p) << (p + 1)) | jp;
            const int ci = jp << (3 - p);
            const float2 T = cmul(W[p], make_float2(CT[ci], -ST[ci]));
            float2 a = r[j], b = r[j + (1 << p)];
            r[j] = make_float2(a.x + b.x, a.y + b.y);
            float2 d = make_float2(a.x - b.x, a.y - b.y);
            r[j + (1 << p)] = cmul(d, T);
        }
    }
}

// Inverse DIT stages p = 0..PMAX. T = W[p]*exp(+i*pi*jp/2^p).
template<int PMAX>
__device__ __forceinline__ void fft16_dit(float2* r, float phi) {
    DECL_TW_TABLES
    float2 W[4];
    if (PMAX == 3) {
        __sincosf(phi, &W[3].y, &W[3].x);
        W[2] = csqr(W[3]); W[1] = csqr(W[2]); W[0] = csqr(W[1]);
    } else {
        W[0] = W[1] = W[2] = W[3] = make_float2(1.f, 0.f);
    }
    #pragma unroll
    for (int p = 0; p <= PMAX; ++p) {
        #pragma unroll
        for (int h = 0; h < 8; ++h) {
            const int jp = h & ((1 << p) - 1);
            const int j  = ((h >> p) << (p + 1)) | jp;
            const int ci = jp << (3 - p);
            const float2 T = cmul(W[p], make_float2(CT[ci], ST[ci]));
            float2 a = r[j];
            float2 b = cmul(r[j + (1 << p)], T);
            r[j]            = make_float2(a.x + b.x, a.y + b.y);
            r[j + (1 << p)] = make_float2(a.x - b.x, a.y - b.y);
        }
    }
}

__launch_bounds__(BLOCK)
__global__ void cbp_fft_kernel(const float* __restrict__ x1,
                               const float* __restrict__ x2,
                               const int* __restrict__ h1,
                               const float* __restrict__ s1,
                               float* __restrict__ out) {
    __shared__ float2 zz[LDS_SLOTS];   // 139264 B
    const int tid = threadIdx.x;
    const int b   = blockIdx.x;

    // ---- zero sketch (including pad slots) ----
    #pragma unroll
    for (int i = tid; i < LDS_SLOTS; i += BLOCK) zz[i] = make_float2(0.f, 0.f);
    __syncthreads();

    // ---- count-sketch scatter ----
    const float* x1r = x1 + (size_t)b * DIM;
    const float* x2r = x2 + (size_t)b * DIM;
    #pragma unroll
    for (int i = 0; i < DIM / BLOCK; ++i) {
        int d = tid + i * BLOCK;
        float s = s1[d];
        int   h = h1[d];
        atomicAdd(&zz[SLOT(h)].x, s * x1r[d]);
        atomicAdd(&zz[SLOT(h)].y, s * x2r[d]);
    }
    __syncthreads();

    float2 r[16];

    // ======== forward DIF: stages m=8192..1024 (group A, stride 1024) ========
    #pragma unroll
    for (int j = 0; j < 16; ++j) r[j] = zz[SLOT(tid + (j << 10))];
    fft16_dif<3>(r, (float)tid * (-3.14159265358979323846f / 8192.f));
    #pragma unroll
    for (int j = 0; j < 16; ++j) zz[SLOT(tid + (j << 10))] = r[j];
    __syncthreads();

    // ======== m=512..64 (group B, stride 64) ========
    {
        const int base = ((tid >> 6) << 10) | (tid & 63);
        #pragma unroll
        for (int j = 0; j < 16; ++j) r[j] = zz[SLOT(base + (j << 6))];
        fft16_dif<3>(r, (float)(tid & 63) * (-3.14159265358979323846f / 512.f));
        #pragma unroll
        for (int j = 0; j < 16; ++j) zz[SLOT(base + (j << 6))] = r[j];
    }
    __syncthreads();

    // ======== m=32..4 (group C, stride 4) ========
    {
        const int base = ((tid >> 2) << 6) | (tid & 3);
        #pragma unroll
        for (int j = 0; j < 16; ++j) r[j] = zz[SLOT(base + (j << 2))];
        fft16_dif<3>(r, (float)(tid & 3) * (-3.14159265358979323846f / 32.f));
        #pragma unroll
        for (int j = 0; j < 16; ++j) zz[SLOT(base + (j << 2))] = r[j];
    }
    __syncthreads();

    // ======== m=2,1 (group D, stride 1) ========
    {
        const int base = tid << 4;
        #pragma unroll
        for (int j = 0; j < 16; ++j) r[j] = zz[SLOT(base + j)];
        fft16_dif<1>(r, 0.f);
        #pragma unroll
        for (int j = 0; j < 16; ++j) zz[SLOT(base + j)] = r[j];
    }
    __syncthreads();

    // ======== pointwise product in bit-reversed domain ========
    #pragma unroll
    for (int jj = 0; jj < FFT_N / BLOCK; ++jj) {
        int j  = tid + jj * BLOCK;
        int f  = (int)(__brev((unsigned)j) >> (32 - LOGN));
        int fp = (FFT_N - f) & (FFT_N - 1);
        if (f < fp) {
            int jp = (int)(__brev((unsigned)fp) >> (32 - LOGN));
            float2 a = zz[SLOT(j)];    // Z[f]
            float2 c = zz[SLOT(jp)];   // Z[N-f]
            float ar = a.x * a.x - a.y * a.y;
            float cr = c.x * c.x - c.y * c.y;
            float xr = ar - cr;
            float xi = 2.f * (a.x * a.y + c.x * c.y);
            zz[SLOT(j)]  = make_float2(0.25f * xi, -0.25f * xr);
            zz[SLOT(jp)] = make_float2(0.25f * xi,  0.25f * xr);
        } else if (f == fp) {
            float2 a = zz[SLOT(j)];
            zz[SLOT(j)] = make_float2(a.x * a.y, 0.f);
        }
    }
    __syncthreads();

    // ======== inverse DIT: m=1,2 (group D', stride 1) ========
    {
        const int base = tid << 4;
        #pragma unroll
        for (int j = 0; j < 16; ++j) r[j] = zz[SLOT(base + j)];
        fft16_dit<1>(r, 0.f);
        #pragma unroll
        for (int j = 0; j < 16; ++j) zz[SLOT(base + j)] = r[j];
    }
    __syncthreads();

    // ======== m=4..32 (group C', stride 4) ========
    {
        const int base = ((tid >> 2) << 6) | (tid & 3);
        #pragma unroll
        for (int j = 0; j < 16; ++j) r[j] = zz[SLOT(base + (j << 2))];
        fft16_dit<3>(r, (float)(tid & 3) * (3.14159265358979323846f / 32.f));
        #pragma unroll
        for (int j = 0; j < 16; ++j) zz[SLOT(base + (j << 2))] = r[j];
    }
    __syncthreads();

    // ======== m=64..512 (group B', stride 64) ========
    {
        const int base = ((tid >> 6) << 10) | (tid & 63);
        #pragma unroll
        for (int j = 0; j < 16; ++j) r[j] = zz[SLOT(base + (j << 6))];
        fft16_dit<3>(r, (float)(tid & 63) * (3.14159265358979323846f / 512.f));
        #pragma unroll
        for (int j = 0; j < 16; ++j) zz[SLOT(base + (j << 6))] = r[j];
    }
    __syncthreads();

    // ======== m=1024..8192 (group A', stride 1024) + fused global store ====
    #pragma unroll
    for (int j = 0; j < 16; ++j) r[j] = zz[SLOT(tid + (j << 10))];
    fft16_dit<3>(r, (float)tid * (3.14159265358979323846f / 8192.f));

    float* outr = out + (size_t)b * FFT_N;
    const float inv_n = 1.0f / (float)FFT_N;
    #pragma unroll
    for (int j = 0; j < 16; ++j) {
        outr[tid + (j << 10)] = r[j].x * inv_n;
    }
}

extern "C" void kernel_launch(void* const* d_in, const int* in_sizes, int n_in,
                              void* d_out, int out_size, void* d_ws, size_t ws_size,
                              hipStream_t stream) {
    const float* x1 = (const float*)d_in[0];
    const float* x2 = (const float*)d_in[1];
    const int*   h1 = (const int*)d_in[2];
    const float* s1 = (const float*)d_in[3];
    float* out = (float*)d_out;
    const int B = in_sizes[0] / DIM;   // 256
    cbp_fft_kernel<<<B, BLOCK, 0, stream>>>(x1, x2, h1, s1, out);
}